// Round 1
// baseline (78.733 us; speedup 1.0000x reference)
//
#include <hip/hip_runtime.h>
#include <math.h>

#define EPS_F 1e-6f
#define CLIP_HI 0.999999f
#define IMG_W 224
#define IMG_H 224
#define ROWF (IMG_W * 3)   // 672 floats per (b,h) row

__device__ __forceinline__ float clip01(float u) {
    return fminf(fmaxf(u, EPS_F), CLIP_HI);
}

// One-thread kernel: resolve the discrete decisions into 2 stage descriptors.
// dec layout (8 floats): [active0, a0, b0, m0, active1, a1, b1, m1]
// Stage backmap (when active): src_x = rint((float)w + (a*h + b)), valid iff 0<=src_x<W.
__global__ void decide_kernel(const float* __restrict__ spw,
                              const float* __restrict__ spp,
                              const float* __restrict__ spm,
                              const float* __restrict__ ug,
                              const float* __restrict__ ul,
                              float* __restrict__ dec) {
    if (threadIdx.x != 0 || blockIdx.x != 0) return;
    for (int i = 0; i < 2; ++i) {
        // gumbel-softmax hard -> argmax(logits + g)
        float g0 = -logf(-logf(clip01(ug[i * 2 + 0])));
        float g1 = -logf(-logf(clip01(ug[i * 2 + 1])));
        int j = (spw[i * 2 + 0] + g0 >= spw[i * 2 + 1] + g1) ? 0 : 1;
        // relaxed bernoulli hard -> rint(sigmoid(logit(p) + logit(u)))
        float p = clip01(spp[i * 2 + j]);
        float uc = clip01(ul[i * 2 + j]);
        float l = logf(uc) - log1pf(-uc);
        float s = (logf(p) - log1pf(-p)) + l;   // tau = 1
        float y = 1.0f / (1.0f + expf(-s));
        int hw = (int)rintf(y);                  // half-to-even like jnp.round
        float m = spm[i * 2 + j];
        float active = 0.f, a = 0.f, b = 0.f;
        if (hw == 1) {
            active = 1.f;
            if (j == 0) {            // shear_x: x_src = w + (0.6m-0.3)*h
                a = 0.6f * m - 0.3f;
                b = 0.f;
            } else {                 // translate_x: x_src = w - (20m-10)
                a = 0.f;
                b = -(20.0f * m - 10.0f);
            }
        }
        dec[i * 4 + 0] = active;
        dec[i * 4 + 1] = a;
        dec[i * 4 + 2] = b;
        dec[i * 4 + 3] = m;
    }
}

// One thread per output float4 (rows are 672 floats = 168 float4, so a float4
// never straddles a row). Gather along W within the same row, zero-fill OOB,
// apply the per-stage value map ((v+m0)-m0+m1)-m1.
__global__ __launch_bounds__(256) void warp_kernel(const float* __restrict__ x,
                                                   const float* __restrict__ dec,
                                                   float* __restrict__ out,
                                                   int total_q) {
    int q = blockIdx.x * 256 + threadIdx.x;
    if (q >= total_q) return;
    int pos = q * 4;                  // global float index
    int row = pos / ROWF;             // b*H + h
    int within = pos - row * ROWF;    // float offset within row
    int h = row % IMG_H;
    int base = row * ROWF;

    // wave-uniform decision scalars (L1/sL1 broadcast)
    const float act0 = dec[0], a0 = dec[1], b0 = dec[2], m0 = dec[3];
    const float act1 = dec[4], a1 = dec[5], b1 = dec[6], m1 = dec[7];
    const bool stage1_on = (act1 != 0.f);
    const bool stage0_on = (act0 != 0.f);
    const float hf = (float)h;

    float r[4];
#pragma unroll
    for (int e = 0; e < 4; ++e) {
        int p = within + e;
        int w = p / 3;
        // back-map through stage 1 (applied second, inverted first)
        int w1 = w;
        bool v = true;
        if (stage1_on) {
            float xs = (float)w + (a1 * hf + b1);
            float xr = rintf(xs);
            int xi = (int)xr;
            v = (xi >= 0) && (xi < IMG_W);
            w1 = xi;
        }
        // back-map through stage 0
        int w0 = w1;
        if (stage0_on) {
            float xs = (float)w1 + (a0 * hf + b0);
            float xr = rintf(xs);
            int xi = (int)xr;
            v = v && (xi >= 0) && (xi < IMG_W);
            w0 = xi;
        }
        float val = 0.f;
        if (v) {
            val = x[base + p + 3 * (w0 - w)];
            val = (((val + m0) - m0) + m1) - m1;  // per-stage value map, fp-exact
        }
        r[e] = val;
    }
    *reinterpret_cast<float4*>(&out[pos]) = make_float4(r[0], r[1], r[2], r[3]);
}

extern "C" void kernel_launch(void* const* d_in, const int* in_sizes, int n_in,
                              void* d_out, int out_size, void* d_ws, size_t ws_size,
                              hipStream_t stream) {
    const float* x   = (const float*)d_in[0];
    const float* spw = (const float*)d_in[1];
    const float* spp = (const float*)d_in[2];
    const float* spm = (const float*)d_in[3];
    const float* ug  = (const float*)d_in[4];
    const float* ul  = (const float*)d_in[5];
    float* dec = (float*)d_ws;
    float* out = (float*)d_out;

    decide_kernel<<<1, 1, 0, stream>>>(spw, spp, spm, ug, ul, dec);

    int total_q = out_size / 4;                 // out_size divisible by 4
    int blocks = (total_q + 255) / 256;
    warp_kernel<<<blocks, 256, 0, stream>>>(x, dec, out, total_q);
}